// Round 2
// baseline (805.226 us; speedup 1.0000x reference)
//
#include <hip/hip_runtime.h>
#include <hip/hip_bf16.h>
#include <math.h>

#define N_GRAPHS 256
#define NODES_PER 100
#define NN (N_GRAPHS * NODES_PER)   // 25600
#define DEG 8
#define FD 128
#define LAT 256
#define HFD 512                      // HEADS * F_DIM
#define MAXPOS 180
#define NEG_SLOPE 0.2f

// ---------------------------------------------------------------- sinusoid table
__global__ void sintab_kernel(float* __restrict__ tab) {
    int p = blockIdx.x;        // 0..179
    int j = threadIdx.x;       // 0..127
    double ang = (double)p / pow(10000.0, (double)(2 * (j / 2)) / 128.0);
    double v = (j & 1) ? cos(ang) : sin(ang);
    tab[p * FD + j] = (float)v;
}

// ---------------------------------------------------------------- g0 = z @ W0 + b0   [256,128]
__global__ void g0_kernel(const float* __restrict__ z, const float* __restrict__ W0,
                          const float* __restrict__ b0, float* __restrict__ g0) {
    __shared__ float s_z[LAT];
    int g = blockIdx.x;        // 0..255
    int j = threadIdx.x;       // 0..127
    s_z[j]       = z[g * LAT + j];
    s_z[j + 128] = z[g * LAT + 128 + j];
    __syncthreads();
    float acc = 0.f;
    #pragma unroll 8
    for (int k = 0; k < LAT; ++k)
        acc += s_z[k] * W0[k * FD + j];
    g0[g * FD + j] = acc + b0[j];
}

// ---------------------------------------------------------------- x1 = relu(concat(g0[batch], pos[order]))  [N,256]
__global__ void build_x1_kernel(const float* __restrict__ g0, const float* __restrict__ tab,
                                const int* __restrict__ batch, float* __restrict__ x1) {
    __shared__ int s_b, s_ord;
    int i = blockIdx.x;
    int t = threadIdx.x;       // 0..255
    if (t == 0) {
        int b = batch[i];
        int lo = 0, hi = i;
        while (lo < hi) { int mid = (lo + hi) >> 1; if (batch[mid] < b) lo = mid + 1; else hi = mid; }
        s_b = b;
        s_ord = i - lo;
    }
    __syncthreads();
    float v = (t < 128) ? g0[s_b * FD + t] : tab[s_ord * FD + (t - 128)];
    x1[(size_t)i * 256 + t] = fmaxf(v, 0.f);
}

// ---------------------------------------------------------------- tiled f32 GEMM: Y[M,ncols] = X[M,K] @ W[K,ncols] (+bias, relu)
template <int BIAS_RELU>
__global__ __launch_bounds__(256) void gemm_kernel(
    const float* __restrict__ X, int ldx,
    const float* __restrict__ W, int ldw,
    const float* __restrict__ bias,
    float* __restrict__ Y, int ldy, int K) {
    __shared__ float As[16][68];   // [k][row]
    __shared__ float Bs[16][68];   // [k][col]
    const int tid  = threadIdx.x;
    const int row0 = blockIdx.x * 64;
    const int col0 = blockIdx.y * 64;
    const int ty = tid >> 4, tx = tid & 15;
    const int arow = tid >> 2;            // 0..63
    const int akq  = (tid & 3) << 2;      // 0,4,8,12
    const int bc   = tid & 63;            // 0..63
    const int bkq  = (tid >> 6) << 2;     // 0,4,8,12
    float acc[4][4] = {};
    for (int k0 = 0; k0 < K; k0 += 16) {
        float4 xv = *(const float4*)&X[(size_t)(row0 + arow) * ldx + k0 + akq];
        As[akq + 0][arow] = xv.x;
        As[akq + 1][arow] = xv.y;
        As[akq + 2][arow] = xv.z;
        As[akq + 3][arow] = xv.w;
        #pragma unroll
        for (int jj = 0; jj < 4; ++jj)
            Bs[bkq + jj][bc] = W[(size_t)(k0 + bkq + jj) * ldw + col0 + bc];
        __syncthreads();
        #pragma unroll
        for (int kk = 0; kk < 16; ++kk) {
            float4 a = *(const float4*)&As[kk][ty << 2];
            float4 b = *(const float4*)&Bs[kk][tx << 2];
            acc[0][0] += a.x * b.x; acc[0][1] += a.x * b.y; acc[0][2] += a.x * b.z; acc[0][3] += a.x * b.w;
            acc[1][0] += a.y * b.x; acc[1][1] += a.y * b.y; acc[1][2] += a.y * b.z; acc[1][3] += a.y * b.w;
            acc[2][0] += a.z * b.x; acc[2][1] += a.z * b.y; acc[2][2] += a.z * b.z; acc[2][3] += a.z * b.w;
            acc[3][0] += a.w * b.x; acc[3][1] += a.w * b.y; acc[3][2] += a.w * b.z; acc[3][3] += a.w * b.w;
        }
        __syncthreads();
    }
    #pragma unroll
    for (int i2 = 0; i2 < 4; ++i2) {
        int r = row0 + (ty << 2) + i2;
        #pragma unroll
        for (int j2 = 0; j2 < 4; ++j2) {
            int c = col0 + (tx << 2) + j2;
            float v = acc[i2][j2];
            if (BIAS_RELU) { v += bias[c]; v = fmaxf(v, 0.f); }
            Y[(size_t)r * ldy + c] = v;
        }
    }
}

// ---------------------------------------------------------------- s,d per node:  s[n,h]=sum_c xl[n,h,c]*as[h,c]
__global__ void sd_kernel(const float* __restrict__ xl,
                          const float* __restrict__ a_src, const float* __restrict__ a_dst,
                          float* __restrict__ s, float* __restrict__ d) {
    int wave = threadIdx.x >> 6;
    int lane = threadIdx.x & 63;
    int n = blockIdx.x * 4 + wave;
    #pragma unroll
    for (int h = 0; h < 4; ++h) {
        float x0 = xl[(size_t)n * HFD + h * FD + lane];
        float x1 = xl[(size_t)n * HFD + h * FD + 64 + lane];
        float ps = x0 * a_src[h * FD + lane] + x1 * a_src[h * FD + 64 + lane];
        float pd = x0 * a_dst[h * FD + lane] + x1 * a_dst[h * FD + 64 + lane];
        #pragma unroll
        for (int m = 32; m >= 1; m >>= 1) {
            ps += __shfl_xor(ps, m);
            pd += __shfl_xor(pd, m);
        }
        if (lane == 0) { s[n * 4 + h] = ps; d[n * 4 + h] = pd; }
    }
}

// ---------------------------------------------------------------- attention + aggregation (per-node, 9 incoming edges)
__global__ void agg_kernel(const float* __restrict__ xl,
                           const float* __restrict__ s, const float* __restrict__ d,
                           const int* __restrict__ esrc,       // edge_index[0], 8 per node
                           const float* __restrict__ bias,
                           float* __restrict__ xout) {
    __shared__ int   srcs[9];
    __shared__ float ek[9][4];
    __shared__ float alpha[9][4];
    int i = blockIdx.x;
    int t = threadIdx.x;   // 0..127
    if (t < 9) srcs[t] = (t < 8) ? esrc[i * DEG + t] : i;
    __syncthreads();
    if (t < 36) {
        int k = t >> 2, h = t & 3;
        float e = s[srcs[k] * 4 + h] + d[i * 4 + h];
        ek[k][h] = (e >= 0.f) ? e : NEG_SLOPE * e;
    }
    __syncthreads();
    if (t < 4) {
        int h = t;
        float m = -1e30f;
        #pragma unroll
        for (int k = 0; k < 9; ++k) m = fmaxf(m, ek[k][h]);
        float den = 0.f;
        #pragma unroll
        for (int k = 0; k < 9; ++k) { float ex = expf(ek[k][h] - m); alpha[k][h] = ex; den += ex; }
        float inv = 1.f / (den + 1e-16f);
        #pragma unroll
        for (int k = 0; k < 9; ++k) alpha[k][h] *= inv;
    }
    __syncthreads();
    #pragma unroll
    for (int rep = 0; rep < 4; ++rep) {
        int j = t + rep * 128;       // 0..511
        int h = j >> 7;
        float acc = 0.f;
        #pragma unroll
        for (int k = 0; k < 9; ++k)
            acc += alpha[k][h] * xl[(size_t)srcs[k] * HFD + j];
        acc += bias[j];
        xout[(size_t)i * HFD + j] = fmaxf(acc, 0.f);
    }
}

// ---------------------------------------------------------------- final: out = h @ Wf + bf    (h=[N,128], Wf=[128,5])
__global__ void out_kernel(const float* __restrict__ H, const float* __restrict__ Wf,
                           const float* __restrict__ bfv, float* __restrict__ out) {
    int wave = threadIdx.x >> 6;
    int lane = threadIdx.x & 63;
    int n = blockIdx.x * 4 + wave;
    float v0 = H[(size_t)n * FD + lane];
    float v1 = H[(size_t)n * FD + 64 + lane];
    #pragma unroll
    for (int q = 0; q < 5; ++q) {
        float p = v0 * Wf[lane * 5 + q] + v1 * Wf[(lane + 64) * 5 + q];
        #pragma unroll
        for (int m = 32; m >= 1; m >>= 1) p += __shfl_xor(p, m);
        if (lane == 0) out[n * 5 + q] = p + bfv[q];
    }
}

// ----------------------------------------------------------------
extern "C" void kernel_launch(void* const* d_in, const int* in_sizes, int n_in,
                              void* d_out, int out_size, void* d_ws, size_t ws_size,
                              hipStream_t stream) {
    const float* z    = (const float*)d_in[0];
    const int*  eidx  = (const int*)d_in[1];    // [2, 204800]; row 0 = src
    const int*  batch = (const int*)d_in[2];
    const float* W0  = (const float*)d_in[3];
    const float* b0  = (const float*)d_in[4];
    const float* W1  = (const float*)d_in[5];
    const float* as1 = (const float*)d_in[6];
    const float* ad1 = (const float*)d_in[7];
    const float* b1  = (const float*)d_in[8];
    const float* W2  = (const float*)d_in[9];
    const float* as2 = (const float*)d_in[10];
    const float* ad2 = (const float*)d_in[11];
    const float* b2  = (const float*)d_in[12];
    const float* W3  = (const float*)d_in[13];
    const float* as3 = (const float*)d_in[14];
    const float* ad3 = (const float*)d_in[15];
    const float* b3  = (const float*)d_in[16];
    const float* Wg  = (const float*)d_in[17];
    const float* bg  = (const float*)d_in[18];
    const float* Wf  = (const float*)d_in[19];
    const float* bfv = (const float*)d_in[20];
    float* out = (float*)d_out;

    float* ws   = (float*)d_ws;
    float* tab  = ws;                          // 180*128      = 23040
    float* g0   = tab + 23040;                 // 256*128      = 32768
    float* sbuf = g0 + 32768;                  // N*4          = 102400
    float* dbuf = sbuf + (size_t)NN * 4;       // N*4
    float* bufA = dbuf + (size_t)NN * 4;       // N*512
    float* bufB = bufA + (size_t)NN * 512;     // N*512

    sintab_kernel<<<MAXPOS, FD, 0, stream>>>(tab);
    g0_kernel<<<N_GRAPHS, FD, 0, stream>>>(z, W0, b0, g0);
    build_x1_kernel<<<NN, 256, 0, stream>>>(g0, tab, batch, bufA);   // x1 [N,256] in bufA

    // ---- layer 1 (K=256)
    gemm_kernel<0><<<dim3(NN / 64, HFD / 64), 256, 0, stream>>>(bufA, 256, W1, HFD, nullptr, bufB, HFD, 256);
    sd_kernel<<<NN / 4, 256, 0, stream>>>(bufB, as1, ad1, sbuf, dbuf);
    agg_kernel<<<NN, 128, 0, stream>>>(bufB, sbuf, dbuf, eidx, b1, bufA);

    // ---- layer 2 (K=512)
    gemm_kernel<0><<<dim3(NN / 64, HFD / 64), 256, 0, stream>>>(bufA, HFD, W2, HFD, nullptr, bufB, HFD, HFD);
    sd_kernel<<<NN / 4, 256, 0, stream>>>(bufB, as2, ad2, sbuf, dbuf);
    agg_kernel<<<NN, 128, 0, stream>>>(bufB, sbuf, dbuf, eidx, b2, bufA);

    // ---- layer 3 (K=512)
    gemm_kernel<0><<<dim3(NN / 64, HFD / 64), 256, 0, stream>>>(bufA, HFD, W3, HFD, nullptr, bufB, HFD, HFD);
    sd_kernel<<<NN / 4, 256, 0, stream>>>(bufB, as3, ad3, sbuf, dbuf);
    agg_kernel<<<NN, 128, 0, stream>>>(bufB, sbuf, dbuf, eidx, b3, bufA);

    // ---- gather head: h = relu(x @ Wg + bg)   [N,128]
    gemm_kernel<1><<<dim3(NN / 64, FD / 64), 256, 0, stream>>>(bufA, HFD, Wg, FD, bg, bufB, FD, HFD);

    // ---- final projection [N,5] -> bf16
    out_kernel<<<NN / 4, 256, 0, stream>>>(bufB, Wf, bfv, out);
}

// Round 3
// 426.053 us; speedup vs baseline: 1.8900x; 1.8900x over previous
//
#include <hip/hip_runtime.h>
#include <hip/hip_bf16.h>
#include <math.h>

#define N_GRAPHS 256
#define NODES_PER 100
#define NN (N_GRAPHS * NODES_PER)   // 25600
#define DEG 8
#define FD 128
#define LAT 256
#define HFD 512                      // HEADS * F_DIM
#define MAXPOS 180
#define NEG_SLOPE 0.2f

typedef _Float16 half8 __attribute__((ext_vector_type(8)));
typedef float float4v __attribute__((ext_vector_type(4)));

// ---------------------------------------------------------------- sinusoid table
__global__ void sintab_kernel(float* __restrict__ tab) {
    int p = blockIdx.x;        // 0..179
    int j = threadIdx.x;       // 0..127
    double ang = (double)p / pow(10000.0, (double)(2 * (j / 2)) / 128.0);
    double v = (j & 1) ? cos(ang) : sin(ang);
    tab[p * FD + j] = (float)v;
}

// ---------------------------------------------------------------- g0 = z @ W0 + b0   [256,128]
__global__ void g0_kernel(const float* __restrict__ z, const float* __restrict__ W0,
                          const float* __restrict__ b0, float* __restrict__ g0) {
    __shared__ float s_z[LAT];
    int g = blockIdx.x;
    int j = threadIdx.x;
    s_z[j]       = z[g * LAT + j];
    s_z[j + 128] = z[g * LAT + 128 + j];
    __syncthreads();
    float acc = 0.f;
    #pragma unroll 8
    for (int k = 0; k < LAT; ++k)
        acc += s_z[k] * W0[k * FD + j];
    g0[g * FD + j] = acc + b0[j];
}

// ---------------------------------------------------------------- x1 = relu(concat(g0[batch], pos[order]))  [N,256] fp16
__global__ void build_x1_kernel(const float* __restrict__ g0, const float* __restrict__ tab,
                                const int* __restrict__ batch, _Float16* __restrict__ x1) {
    __shared__ int s_b, s_ord;
    int i = blockIdx.x;
    int t = threadIdx.x;       // 0..255
    if (t == 0) {
        int b = batch[i];
        int lo = 0, hi = i;
        while (lo < hi) { int mid = (lo + hi) >> 1; if (batch[mid] < b) lo = mid + 1; else hi = mid; }
        s_b = b;
        s_ord = i - lo;
    }
    __syncthreads();
    float v = (t < 128) ? g0[s_b * FD + t] : tab[s_ord * FD + (t - 128)];
    x1[(size_t)i * 256 + t] = (_Float16)fmaxf(v, 0.f);
}

// ---------------------------------------------------------------- weight transpose+convert: in f32 [K][Nw] -> out fp16 [Nw][K]
__global__ void wconv_kernel(const float* __restrict__ in, _Float16* __restrict__ out,
                             int K, int Nw) {
    __shared__ float tile[32][33];
    int kb = blockIdx.y * 32, nb = blockIdx.x * 32;
    int tx = threadIdx.x & 31, ty = threadIdx.x >> 5;   // 32 x 8
    #pragma unroll
    for (int r = 0; r < 4; ++r)
        tile[ty + 8 * r][tx] = in[(size_t)(kb + ty + 8 * r) * Nw + nb + tx];
    __syncthreads();
    #pragma unroll
    for (int r = 0; r < 4; ++r)
        out[(size_t)(nb + ty + 8 * r) * K + kb + tx] = (_Float16)tile[tx][ty + 8 * r];
}

// ---------------------------------------------------------------- fp16 MFMA GEMM: Y[M][ldy] f32 = X[M][K] fp16 @ Wt[N][K]^T fp16
template <int BIAS_RELU>
__global__ __launch_bounds__(256) void hgemm_kernel(
    const _Float16* __restrict__ X,   // [M][K] row-major
    const _Float16* __restrict__ Wt,  // [N][K] row-major (i.e. W transposed)
    const float* __restrict__ bias,   // [ldy] or null
    float* __restrict__ Y,            // [M][ldy]
    int K, int ldy) {
    __shared__ __align__(16) _Float16 As[2][128 * 32];
    __shared__ __align__(16) _Float16 Bs[2][128 * 32];
    const int tid  = threadIdx.x;
    const int lane = tid & 63;
    const int wave = tid >> 6;       // 0..3
    const int wm = wave >> 1;        // row half
    const int wn = wave & 1;         // col half
    const int row0 = blockIdx.y * 128;
    const int col0 = blockIdx.x * 128;

    // staging: thread t covers row sr, k-slots sq,sq+1 (16 halves = 32B)
    const int sr = tid >> 1;
    const int sq = (tid & 1) * 2;
    const size_t ga = (size_t)(row0 + sr) * K + sq * 8;
    const size_t gb = (size_t)(col0 + sr) * K + sq * 8;
    const int ss = (sr >> 1) & 3;
    const int w0 = sr * 32 + ((sq ^ ss) * 8);
    const int w1 = sr * 32 + (((sq + 1) ^ ss) * 8);

    const int q = lane >> 4;         // k-group 0..3
    const int l15 = lane & 15;

    float4v acc[4][4];
    #pragma unroll
    for (int i = 0; i < 4; ++i)
        #pragma unroll
        for (int j = 0; j < 4; ++j)
            acc[i][j] = (float4v){0.f, 0.f, 0.f, 0.f};

    half8 ra0, ra1, rb0, rb1;
    ra0 = *(const half8*)&X[ga];      ra1 = *(const half8*)&X[ga + 8];
    rb0 = *(const half8*)&Wt[gb];     rb1 = *(const half8*)&Wt[gb + 8];
    *(half8*)&As[0][w0] = ra0;  *(half8*)&As[0][w1] = ra1;
    *(half8*)&Bs[0][w0] = rb0;  *(half8*)&Bs[0][w1] = rb1;

    const int nk = K >> 5;
    for (int ks = 0; ks < nk; ++ks) {
        __syncthreads();
        const int cur = ks & 1;
        if (ks + 1 < nk) {
            int kb = (ks + 1) << 5;
            ra0 = *(const half8*)&X[ga + kb];   ra1 = *(const half8*)&X[ga + kb + 8];
            rb0 = *(const half8*)&Wt[gb + kb];  rb1 = *(const half8*)&Wt[gb + kb + 8];
        }
        half8 af[4], bf[4];
        #pragma unroll
        for (int mi = 0; mi < 4; ++mi) {
            int r = wm * 64 + mi * 16 + l15;
            af[mi] = *(const half8*)&As[cur][r * 32 + ((q ^ ((r >> 1) & 3)) * 8)];
        }
        #pragma unroll
        for (int ni = 0; ni < 4; ++ni) {
            int c = wn * 64 + ni * 16 + l15;
            bf[ni] = *(const half8*)&Bs[cur][c * 32 + ((q ^ ((c >> 1) & 3)) * 8)];
        }
        #pragma unroll
        for (int mi = 0; mi < 4; ++mi)
            #pragma unroll
            for (int ni = 0; ni < 4; ++ni)
                acc[mi][ni] = __builtin_amdgcn_mfma_f32_16x16x32_f16(af[mi], bf[ni], acc[mi][ni], 0, 0, 0);
        if (ks + 1 < nk) {
            const int nxt = cur ^ 1;
            *(half8*)&As[nxt][w0] = ra0;  *(half8*)&As[nxt][w1] = ra1;
            *(half8*)&Bs[nxt][w0] = rb0;  *(half8*)&Bs[nxt][w1] = rb1;
        }
    }

    // epilogue: C/D layout col=lane&15, row=(lane>>4)*4+j
    #pragma unroll
    for (int mi = 0; mi < 4; ++mi) {
        int r = row0 + wm * 64 + mi * 16 + ((lane >> 4) << 2);
        #pragma unroll
        for (int ni = 0; ni < 4; ++ni) {
            int c = col0 + wn * 64 + ni * 16 + l15;
            #pragma unroll
            for (int j = 0; j < 4; ++j) {
                float v = acc[mi][ni][j];
                if (BIAS_RELU) { v += bias[c]; v = fmaxf(v, 0.f); }
                Y[(size_t)(r + j) * ldy + c] = v;
            }
        }
    }
}

// ---------------------------------------------------------------- s,d per node
__global__ void sd_kernel(const float* __restrict__ xl,
                          const float* __restrict__ a_src, const float* __restrict__ a_dst,
                          float* __restrict__ s, float* __restrict__ d) {
    int wave = threadIdx.x >> 6;
    int lane = threadIdx.x & 63;
    int n = blockIdx.x * 4 + wave;
    #pragma unroll
    for (int h = 0; h < 4; ++h) {
        float x0 = xl[(size_t)n * HFD + h * FD + lane];
        float x1 = xl[(size_t)n * HFD + h * FD + 64 + lane];
        float ps = x0 * a_src[h * FD + lane] + x1 * a_src[h * FD + 64 + lane];
        float pd = x0 * a_dst[h * FD + lane] + x1 * a_dst[h * FD + 64 + lane];
        #pragma unroll
        for (int m = 32; m >= 1; m >>= 1) {
            ps += __shfl_xor(ps, m);
            pd += __shfl_xor(pd, m);
        }
        if (lane == 0) { s[n * 4 + h] = ps; d[n * 4 + h] = pd; }
    }
}

// ---------------------------------------------------------------- attention + aggregation (per-node, 9 incoming edges) -> fp16
__global__ void agg_kernel(const float* __restrict__ xl,
                           const float* __restrict__ s, const float* __restrict__ d,
                           const int* __restrict__ esrc,
                           const float* __restrict__ bias,
                           _Float16* __restrict__ xout) {
    __shared__ int   srcs[9];
    __shared__ float ek[9][4];
    __shared__ float alpha[9][4];
    int i = blockIdx.x;
    int t = threadIdx.x;   // 0..127
    if (t < 9) srcs[t] = (t < 8) ? esrc[i * DEG + t] : i;
    __syncthreads();
    if (t < 36) {
        int k = t >> 2, h = t & 3;
        float e = s[srcs[k] * 4 + h] + d[i * 4 + h];
        ek[k][h] = (e >= 0.f) ? e : NEG_SLOPE * e;
    }
    __syncthreads();
    if (t < 4) {
        int h = t;
        float m = -1e30f;
        #pragma unroll
        for (int k = 0; k < 9; ++k) m = fmaxf(m, ek[k][h]);
        float den = 0.f;
        #pragma unroll
        for (int k = 0; k < 9; ++k) { float ex = expf(ek[k][h] - m); alpha[k][h] = ex; den += ex; }
        float inv = 1.f / (den + 1e-16f);
        #pragma unroll
        for (int k = 0; k < 9; ++k) alpha[k][h] *= inv;
    }
    __syncthreads();
    #pragma unroll
    for (int rep = 0; rep < 4; ++rep) {
        int j = t + rep * 128;       // 0..511
        int h = j >> 7;
        float acc = 0.f;
        #pragma unroll
        for (int k = 0; k < 9; ++k)
            acc += alpha[k][h] * xl[(size_t)srcs[k] * HFD + j];
        acc += bias[j];
        xout[(size_t)i * HFD + j] = (_Float16)fmaxf(acc, 0.f);
    }
}

// ---------------------------------------------------------------- final: out = h @ Wf + bf
__global__ void out_kernel(const float* __restrict__ H, const float* __restrict__ Wf,
                           const float* __restrict__ bfv, float* __restrict__ out) {
    int wave = threadIdx.x >> 6;
    int lane = threadIdx.x & 63;
    int n = blockIdx.x * 4 + wave;
    float v0 = H[(size_t)n * FD + lane];
    float v1 = H[(size_t)n * FD + 64 + lane];
    #pragma unroll
    for (int q = 0; q < 5; ++q) {
        float p = v0 * Wf[lane * 5 + q] + v1 * Wf[(lane + 64) * 5 + q];
        #pragma unroll
        for (int m = 32; m >= 1; m >>= 1) p += __shfl_xor(p, m);
        if (lane == 0) out[n * 5 + q] = p + bfv[q];
    }
}

// ----------------------------------------------------------------
extern "C" void kernel_launch(void* const* d_in, const int* in_sizes, int n_in,
                              void* d_out, int out_size, void* d_ws, size_t ws_size,
                              hipStream_t stream) {
    const float* z    = (const float*)d_in[0];
    const int*  eidx  = (const int*)d_in[1];
    const int*  batch = (const int*)d_in[2];
    const float* W0  = (const float*)d_in[3];
    const float* b0  = (const float*)d_in[4];
    const float* W1  = (const float*)d_in[5];
    const float* as1 = (const float*)d_in[6];
    const float* ad1 = (const float*)d_in[7];
    const float* b1  = (const float*)d_in[8];
    const float* W2  = (const float*)d_in[9];
    const float* as2 = (const float*)d_in[10];
    const float* ad2 = (const float*)d_in[11];
    const float* b2  = (const float*)d_in[12];
    const float* W3  = (const float*)d_in[13];
    const float* as3 = (const float*)d_in[14];
    const float* ad3 = (const float*)d_in[15];
    const float* b3  = (const float*)d_in[16];
    const float* Wg  = (const float*)d_in[17];
    const float* bg  = (const float*)d_in[18];
    const float* Wf  = (const float*)d_in[19];
    const float* bfv = (const float*)d_in[20];
    float* out = (float*)d_out;

    float* ws   = (float*)d_ws;
    float* tab  = ws;                          // 23040
    float* g0   = tab + 23040;                 // 32768
    float* sbuf = g0 + 32768;                  // 102400
    float* dbuf = sbuf + (size_t)NN * 4;       // 102400
    float* Ybuf = dbuf + (size_t)NN * 4;       // N*512 f32
    float* Hbuf = Ybuf + (size_t)NN * 512;     // N*128 f32
    _Float16* Xh  = (_Float16*)(Hbuf + (size_t)NN * 128);  // N*512 fp16
    _Float16* W1t = Xh + (size_t)NN * 512;     // 512*256
    _Float16* W2t = W1t + 512 * 256;           // 512*512
    _Float16* W3t = W2t + 512 * 512;           // 512*512
    _Float16* Wgt = W3t + 512 * 512;           // 128*512

    sintab_kernel<<<MAXPOS, FD, 0, stream>>>(tab);
    g0_kernel<<<N_GRAPHS, FD, 0, stream>>>(z, W0, b0, g0);
    build_x1_kernel<<<NN, 256, 0, stream>>>(g0, tab, batch, Xh);

    // weight transpose+convert (f32 [K][N] -> fp16 [N][K])
    wconv_kernel<<<dim3(512 / 32, 256 / 32), 256, 0, stream>>>(W1, W1t, 256, 512);
    wconv_kernel<<<dim3(512 / 32, 512 / 32), 256, 0, stream>>>(W2, W2t, 512, 512);
    wconv_kernel<<<dim3(512 / 32, 512 / 32), 256, 0, stream>>>(W3, W3t, 512, 512);
    wconv_kernel<<<dim3(128 / 32, 512 / 32), 256, 0, stream>>>(Wg, Wgt, 512, 128);

    // ---- layer 1 (K=256)
    hgemm_kernel<0><<<dim3(HFD / 128, NN / 128), 256, 0, stream>>>(Xh, W1t, nullptr, Ybuf, 256, HFD);
    sd_kernel<<<NN / 4, 256, 0, stream>>>(Ybuf, as1, ad1, sbuf, dbuf);
    agg_kernel<<<NN, 128, 0, stream>>>(Ybuf, sbuf, dbuf, eidx, b1, Xh);

    // ---- layer 2 (K=512)
    hgemm_kernel<0><<<dim3(HFD / 128, NN / 128), 256, 0, stream>>>(Xh, W2t, nullptr, Ybuf, 512, HFD);
    sd_kernel<<<NN / 4, 256, 0, stream>>>(Ybuf, as2, ad2, sbuf, dbuf);
    agg_kernel<<<NN, 128, 0, stream>>>(Ybuf, sbuf, dbuf, eidx, b2, Xh);

    // ---- layer 3 (K=512)
    hgemm_kernel<0><<<dim3(HFD / 128, NN / 128), 256, 0, stream>>>(Xh, W3t, nullptr, Ybuf, 512, HFD);
    sd_kernel<<<NN / 4, 256, 0, stream>>>(Ybuf, as3, ad3, sbuf, dbuf);
    agg_kernel<<<NN, 128, 0, stream>>>(Ybuf, sbuf, dbuf, eidx, b3, Xh);

    // ---- gather head: h = relu(x @ Wg + bg)   [N,128]
    hgemm_kernel<1><<<dim3(FD / 128, NN / 128), 256, 0, stream>>>(Xh, Wgt, bg, Hbuf, 512, FD);

    // ---- final projection [N,5]
    out_kernel<<<NN / 4, 256, 0, stream>>>(Hbuf, Wf, bfv, out);
}

// Round 4
// 302.845 us; speedup vs baseline: 2.6589x; 1.4068x over previous
//
#include <hip/hip_runtime.h>
#include <hip/hip_bf16.h>
#include <math.h>

#define N_GRAPHS 256
#define NODES_PER 100
#define NN (N_GRAPHS * NODES_PER)   // 25600
#define DEG 8
#define FD 128
#define LAT 256
#define HFD 512                      // HEADS * F_DIM
#define MAXPOS 180
#define NEG_SLOPE 0.2f

typedef _Float16 half8 __attribute__((ext_vector_type(8)));
typedef float float4v __attribute__((ext_vector_type(4)));

// XCD-contiguous chunk swizzle; requires total % 8 == 0 (bijective)
__device__ __forceinline__ int xcd_swz(int bid, int total) {
    int q = total >> 3;
    return (bid & 7) * q + (bid >> 3);
}

// ---------------------------------------------------------------- sinusoid table
__global__ void sintab_kernel(float* __restrict__ tab) {
    int p = blockIdx.x;        // 0..179
    int j = threadIdx.x;       // 0..127
    double ang = (double)p / pow(10000.0, (double)(2 * (j / 2)) / 128.0);
    double v = (j & 1) ? cos(ang) : sin(ang);
    tab[p * FD + j] = (float)v;
}

// ---------------------------------------------------------------- g0 = z @ W0 + b0   [256,128]
__global__ void g0_kernel(const float* __restrict__ z, const float* __restrict__ W0,
                          const float* __restrict__ b0, float* __restrict__ g0) {
    __shared__ float s_z[LAT];
    int g = blockIdx.x;
    int j = threadIdx.x;
    s_z[j]       = z[g * LAT + j];
    s_z[j + 128] = z[g * LAT + 128 + j];
    __syncthreads();
    float acc = 0.f;
    #pragma unroll 8
    for (int k = 0; k < LAT; ++k)
        acc += s_z[k] * W0[k * FD + j];
    g0[g * FD + j] = acc + b0[j];
}

// ---------------------------------------------------------------- x1 = relu(concat(g0[batch], pos[order]))  [N,256] fp16
__global__ void build_x1_kernel(const float* __restrict__ g0, const float* __restrict__ tab,
                                const int* __restrict__ batch, _Float16* __restrict__ x1) {
    __shared__ int s_b, s_ord;
    int i = blockIdx.x;
    int t = threadIdx.x;       // 0..255
    if (t == 0) {
        int b = batch[i];
        int lo = 0, hi = i;
        while (lo < hi) { int mid = (lo + hi) >> 1; if (batch[mid] < b) lo = mid + 1; else hi = mid; }
        s_b = b;
        s_ord = i - lo;
    }
    __syncthreads();
    float v = (t < 128) ? g0[s_b * FD + t] : tab[s_ord * FD + (t - 128)];
    x1[(size_t)i * 256 + t] = (_Float16)fmaxf(v, 0.f);
}

// ---------------------------------------------------------------- weight transpose+convert: f32 [K][Nw] -> fp16 [Nw][K]
__global__ void wconv_kernel(const float* __restrict__ in, _Float16* __restrict__ out,
                             int K, int Nw) {
    __shared__ float tile[32][33];
    int kb = blockIdx.y * 32, nb = blockIdx.x * 32;
    int tx = threadIdx.x & 31, ty = threadIdx.x >> 5;   // 32 x 8
    #pragma unroll
    for (int r = 0; r < 4; ++r)
        tile[ty + 8 * r][tx] = in[(size_t)(kb + ty + 8 * r) * Nw + nb + tx];
    __syncthreads();
    #pragma unroll
    for (int r = 0; r < 4; ++r)
        out[(size_t)(nb + ty + 8 * r) * K + kb + tx] = (_Float16)tile[tx][ty + 8 * r];
}

// ---------------------------------------------------------------- fp16 MFMA GEMM
// MODE 0: Y fp16, no bias.  MODE 1: Y f32, bias+relu.
template <int MODE>
__global__ __launch_bounds__(256) void hgemm_kernel(
    const _Float16* __restrict__ X,   // [M][K] row-major
    const _Float16* __restrict__ Wt,  // [N][K] row-major
    const float* __restrict__ bias,
    void* __restrict__ Yv,
    int K, int ldy, int nbx) {
    __shared__ __align__(16) _Float16 As[2][128 * 32];
    __shared__ __align__(16) _Float16 Bs[2][128 * 32];
    const int lin = xcd_swz(blockIdx.x, gridDim.x);
    const int row0 = (lin / nbx) * 128;
    const int col0 = (lin % nbx) * 128;
    const int tid  = threadIdx.x;
    const int lane = tid & 63;
    const int wave = tid >> 6;
    const int wm = wave >> 1;
    const int wn = wave & 1;

    const int sr = tid >> 1;
    const int sq = (tid & 1) * 2;
    const size_t ga = (size_t)(row0 + sr) * K + sq * 8;
    const size_t gb = (size_t)(col0 + sr) * K + sq * 8;
    const int ss = (sr >> 1) & 3;
    const int w0 = sr * 32 + ((sq ^ ss) * 8);
    const int w1 = sr * 32 + (((sq + 1) ^ ss) * 8);

    const int kq  = lane >> 4;
    const int l15 = lane & 15;

    float4v acc[4][4];
    #pragma unroll
    for (int i = 0; i < 4; ++i)
        #pragma unroll
        for (int j = 0; j < 4; ++j)
            acc[i][j] = (float4v){0.f, 0.f, 0.f, 0.f};

    half8 ra0, ra1, rb0, rb1;
    ra0 = *(const half8*)&X[ga];      ra1 = *(const half8*)&X[ga + 8];
    rb0 = *(const half8*)&Wt[gb];     rb1 = *(const half8*)&Wt[gb + 8];
    *(half8*)&As[0][w0] = ra0;  *(half8*)&As[0][w1] = ra1;
    *(half8*)&Bs[0][w0] = rb0;  *(half8*)&Bs[0][w1] = rb1;

    const int nk = K >> 5;
    for (int ks = 0; ks < nk; ++ks) {
        __syncthreads();
        const int cur = ks & 1;
        if (ks + 1 < nk) {
            int kb = (ks + 1) << 5;
            ra0 = *(const half8*)&X[ga + kb];   ra1 = *(const half8*)&X[ga + kb + 8];
            rb0 = *(const half8*)&Wt[gb + kb];  rb1 = *(const half8*)&Wt[gb + kb + 8];
        }
        half8 af[4], bf[4];
        #pragma unroll
        for (int mi = 0; mi < 4; ++mi) {
            int r = wm * 64 + mi * 16 + l15;
            af[mi] = *(const half8*)&As[cur][r * 32 + ((kq ^ ((r >> 1) & 3)) * 8)];
        }
        #pragma unroll
        for (int ni = 0; ni < 4; ++ni) {
            int c = wn * 64 + ni * 16 + l15;
            bf[ni] = *(const half8*)&Bs[cur][c * 32 + ((kq ^ ((c >> 1) & 3)) * 8)];
        }
        #pragma unroll
        for (int mi = 0; mi < 4; ++mi)
            #pragma unroll
            for (int ni = 0; ni < 4; ++ni)
                acc[mi][ni] = __builtin_amdgcn_mfma_f32_16x16x32_f16(af[mi], bf[ni], acc[mi][ni], 0, 0, 0);
        if (ks + 1 < nk) {
            const int nxt = cur ^ 1;
            *(half8*)&As[nxt][w0] = ra0;  *(half8*)&As[nxt][w1] = ra1;
            *(half8*)&Bs[nxt][w0] = rb0;  *(half8*)&Bs[nxt][w1] = rb1;
        }
    }

    // epilogue: C/D layout col=lane&15, row=(lane>>4)*4+j
    #pragma unroll
    for (int mi = 0; mi < 4; ++mi) {
        int r = row0 + wm * 64 + mi * 16 + ((lane >> 4) << 2);
        #pragma unroll
        for (int ni = 0; ni < 4; ++ni) {
            int c = col0 + wn * 64 + ni * 16 + l15;
            #pragma unroll
            for (int j = 0; j < 4; ++j) {
                float v = acc[mi][ni][j];
                if (MODE == 1) {
                    v += bias[c]; v = fmaxf(v, 0.f);
                    ((float*)Yv)[(size_t)(r + j) * ldy + c] = v;
                } else {
                    ((_Float16*)Yv)[(size_t)(r + j) * ldy + c] = (_Float16)v;
                }
            }
        }
    }
}

// ---------------------------------------------------------------- s,d per node (wave-per-node, fp16 xl)
__global__ void sd_kernel(const _Float16* __restrict__ xl,
                          const float* __restrict__ a_src, const float* __restrict__ a_dst,
                          float* __restrict__ s, float* __restrict__ d) {
    int wave = threadIdx.x >> 6;
    int lane = threadIdx.x & 63;
    int n = blockIdx.x * 4 + wave;
    int h = lane >> 4;
    int c0 = (lane & 15) * 8;
    half8 x = *(const half8*)&xl[(size_t)n * HFD + h * FD + c0];
    float4v a0 = *(const float4v*)&a_src[h * FD + c0];
    float4v a1 = *(const float4v*)&a_src[h * FD + c0 + 4];
    float4v e0 = *(const float4v*)&a_dst[h * FD + c0];
    float4v e1 = *(const float4v*)&a_dst[h * FD + c0 + 4];
    float ps = 0.f, pd = 0.f;
    #pragma unroll
    for (int j = 0; j < 4; ++j) {
        ps += (float)x[j] * a0[j] + (float)x[j + 4] * a1[j];
        pd += (float)x[j] * e0[j] + (float)x[j + 4] * e1[j];
    }
    #pragma unroll
    for (int m = 8; m >= 1; m >>= 1) {
        ps += __shfl_xor(ps, m);
        pd += __shfl_xor(pd, m);
    }
    if ((lane & 15) == 0) { s[n * 4 + h] = ps; d[n * 4 + h] = pd; }
}

// ---------------------------------------------------------------- attention + aggregation (wave-per-node, fp16)
__global__ void agg_kernel(const _Float16* __restrict__ xl,
                           const float* __restrict__ s, const float* __restrict__ d,
                           const int* __restrict__ esrc,
                           const float* __restrict__ bias,
                           _Float16* __restrict__ xout) {
    int wave = threadIdx.x >> 6;
    int lane = threadIdx.x & 63;
    int blk = xcd_swz(blockIdx.x, gridDim.x);
    int i = blk * 4 + wave;
    int h = lane >> 4;

    int sk = (lane < 8) ? esrc[i * DEG + lane] : i;
    int srcs[9];
    #pragma unroll
    for (int k = 0; k < 9; ++k) srcs[k] = __shfl(sk, k);

    float dh = d[i * 4 + h];
    float e[9];
    float m = -1e30f;
    #pragma unroll
    for (int k = 0; k < 9; ++k) {
        float v = s[srcs[k] * 4 + h] + dh;
        v = (v >= 0.f) ? v : NEG_SLOPE * v;
        e[k] = v;
        m = fmaxf(m, v);
    }
    float den = 0.f;
    #pragma unroll
    for (int k = 0; k < 9; ++k) { e[k] = __expf(e[k] - m); den += e[k]; }
    float inv = 1.f / (den + 1e-16f);

    int c0 = lane * 8;   // 0..504; head = c0>>7 == h
    float acc[8] = {};
    #pragma unroll
    for (int k = 0; k < 9; ++k) {
        half8 x = *(const half8*)&xl[(size_t)srcs[k] * HFD + c0];
        float a = e[k] * inv;
        #pragma unroll
        for (int j = 0; j < 8; ++j) acc[j] += a * (float)x[j];
    }
    float4v b0 = *(const float4v*)&bias[c0];
    float4v b1 = *(const float4v*)&bias[c0 + 4];
    half8 o;
    #pragma unroll
    for (int j = 0; j < 4; ++j) {
        o[j]     = (_Float16)fmaxf(acc[j] + b0[j], 0.f);
        o[j + 4] = (_Float16)fmaxf(acc[j + 4] + b1[j], 0.f);
    }
    *(half8*)&xout[(size_t)i * HFD + c0] = o;
}

// ---------------------------------------------------------------- final: out = h @ Wf + bf
__global__ void out_kernel(const float* __restrict__ H, const float* __restrict__ Wf,
                           const float* __restrict__ bfv, float* __restrict__ out) {
    int wave = threadIdx.x >> 6;
    int lane = threadIdx.x & 63;
    int n = blockIdx.x * 4 + wave;
    float v0 = H[(size_t)n * FD + lane];
    float v1 = H[(size_t)n * FD + 64 + lane];
    #pragma unroll
    for (int q = 0; q < 5; ++q) {
        float p = v0 * Wf[lane * 5 + q] + v1 * Wf[(lane + 64) * 5 + q];
        #pragma unroll
        for (int m = 32; m >= 1; m >>= 1) p += __shfl_xor(p, m);
        if (lane == 0) out[n * 5 + q] = p + bfv[q];
    }
}

// ----------------------------------------------------------------
extern "C" void kernel_launch(void* const* d_in, const int* in_sizes, int n_in,
                              void* d_out, int out_size, void* d_ws, size_t ws_size,
                              hipStream_t stream) {
    const float* z    = (const float*)d_in[0];
    const int*  eidx  = (const int*)d_in[1];
    const int*  batch = (const int*)d_in[2];
    const float* W0  = (const float*)d_in[3];
    const float* b0  = (const float*)d_in[4];
    const float* W1  = (const float*)d_in[5];
    const float* as1 = (const float*)d_in[6];
    const float* ad1 = (const float*)d_in[7];
    const float* b1  = (const float*)d_in[8];
    const float* W2  = (const float*)d_in[9];
    const float* as2 = (const float*)d_in[10];
    const float* ad2 = (const float*)d_in[11];
    const float* b2  = (const float*)d_in[12];
    const float* W3  = (const float*)d_in[13];
    const float* as3 = (const float*)d_in[14];
    const float* ad3 = (const float*)d_in[15];
    const float* b3  = (const float*)d_in[16];
    const float* Wg  = (const float*)d_in[17];
    const float* bg  = (const float*)d_in[18];
    const float* Wf  = (const float*)d_in[19];
    const float* bfv = (const float*)d_in[20];
    float* out = (float*)d_out;

    float* ws   = (float*)d_ws;
    float* tab  = ws;                          // 23040
    float* g0   = tab + 23040;                 // 32768
    float* sbuf = g0 + 32768;                  // NN*4
    float* dbuf = sbuf + (size_t)NN * 4;       // NN*4
    float* Hbuf = dbuf + (size_t)NN * 4;       // NN*128 f32
    _Float16* Yh  = (_Float16*)(Hbuf + (size_t)NN * 128);  // NN*512 fp16
    _Float16* Xh  = Yh + (size_t)NN * 512;     // NN*512 fp16
    _Float16* W1t = Xh + (size_t)NN * 512;     // 512*256
    _Float16* W2t = W1t + 512 * 256;           // 512*512
    _Float16* W3t = W2t + 512 * 512;           // 512*512
    _Float16* Wgt = W3t + 512 * 512;           // 128*512

    sintab_kernel<<<MAXPOS, FD, 0, stream>>>(tab);
    g0_kernel<<<N_GRAPHS, FD, 0, stream>>>(z, W0, b0, g0);
    build_x1_kernel<<<NN, 256, 0, stream>>>(g0, tab, batch, Xh);

    wconv_kernel<<<dim3(512 / 32, 256 / 32), 256, 0, stream>>>(W1, W1t, 256, 512);
    wconv_kernel<<<dim3(512 / 32, 512 / 32), 256, 0, stream>>>(W2, W2t, 512, 512);
    wconv_kernel<<<dim3(512 / 32, 512 / 32), 256, 0, stream>>>(W3, W3t, 512, 512);
    wconv_kernel<<<dim3(128 / 32, 512 / 32), 256, 0, stream>>>(Wg, Wgt, 512, 128);

    const int nbL = (NN / 128) * (HFD / 128);  // 800 blocks, %8==0
    const int nbH = (NN / 128) * (FD / 128);   // 200 blocks, %8==0

    // ---- layer 1 (K=256)
    hgemm_kernel<0><<<nbL, 256, 0, stream>>>(Xh, W1t, nullptr, Yh, 256, HFD, HFD / 128);
    sd_kernel<<<NN / 4, 256, 0, stream>>>(Yh, as1, ad1, sbuf, dbuf);
    agg_kernel<<<NN / 4, 256, 0, stream>>>(Yh, sbuf, dbuf, eidx, b1, Xh);

    // ---- layer 2 (K=512)
    hgemm_kernel<0><<<nbL, 256, 0, stream>>>(Xh, W2t, nullptr, Yh, 512, HFD, HFD / 128);
    sd_kernel<<<NN / 4, 256, 0, stream>>>(Yh, as2, ad2, sbuf, dbuf);
    agg_kernel<<<NN / 4, 256, 0, stream>>>(Yh, sbuf, dbuf, eidx, b2, Xh);

    // ---- layer 3 (K=512)
    hgemm_kernel<0><<<nbL, 256, 0, stream>>>(Xh, W3t, nullptr, Yh, 512, HFD, HFD / 128);
    sd_kernel<<<NN / 4, 256, 0, stream>>>(Yh, as3, ad3, sbuf, dbuf);
    agg_kernel<<<NN / 4, 256, 0, stream>>>(Yh, sbuf, dbuf, eidx, b3, Xh);

    // ---- gather head: h = relu(x @ Wg + bg)   [N,128] f32
    hgemm_kernel<1><<<nbH, 256, 0, stream>>>(Xh, Wgt, bg, Hbuf, 512, FD, FD / 128);

    // ---- final projection [N,5]
    out_kernel<<<NN / 4, 256, 0, stream>>>(Hbuf, Wf, bfv, out);
}

// Round 5
// 294.332 us; speedup vs baseline: 2.7358x; 1.0289x over previous
//
#include <hip/hip_runtime.h>
#include <hip/hip_bf16.h>
#include <math.h>

#define N_GRAPHS 256
#define NODES_PER 100
#define NN (N_GRAPHS * NODES_PER)   // 25600
#define DEG 8
#define FD 128
#define LAT 256
#define HFD 512                      // HEADS * F_DIM
#define MAXPOS 180
#define NEG_SLOPE 0.2f

typedef _Float16 half8 __attribute__((ext_vector_type(8)));
typedef float float4v __attribute__((ext_vector_type(4)));

// XCD-contiguous chunk swizzle; requires total % 8 == 0 (bijective)
__device__ __forceinline__ int xcd_swz(int bid, int total) {
    int q = total >> 3;
    return (bid & 7) * q + (bid >> 3);
}

// ---------------------------------------------------------------- sinusoid table
__global__ void sintab_kernel(float* __restrict__ tab) {
    int p = blockIdx.x;
    int j = threadIdx.x;
    double ang = (double)p / pow(10000.0, (double)(2 * (j / 2)) / 128.0);
    double v = (j & 1) ? cos(ang) : sin(ang);
    tab[p * FD + j] = (float)v;
}

// ---------------------------------------------------------------- g0 = z @ W0 + b0   [256,128]
__global__ void g0_kernel(const float* __restrict__ z, const float* __restrict__ W0,
                          const float* __restrict__ b0, float* __restrict__ g0) {
    __shared__ float s_z[LAT];
    int g = blockIdx.x;
    int j = threadIdx.x;
    s_z[j]       = z[g * LAT + j];
    s_z[j + 128] = z[g * LAT + 128 + j];
    __syncthreads();
    float acc = 0.f;
    #pragma unroll 8
    for (int k = 0; k < LAT; ++k)
        acc += s_z[k] * W0[k * FD + j];
    g0[g * FD + j] = acc + b0[j];
}

// ---------------------------------------------------------------- x1 = relu(concat(g0[batch], pos[order]))  [N,256] fp16
__global__ void build_x1_kernel(const float* __restrict__ g0, const float* __restrict__ tab,
                                const int* __restrict__ batch, _Float16* __restrict__ x1) {
    __shared__ int s_b, s_ord;
    int i = blockIdx.x;
    int t = threadIdx.x;
    if (t == 0) {
        int b = batch[i];
        int lo = 0, hi = i;
        while (lo < hi) { int mid = (lo + hi) >> 1; if (batch[mid] < b) lo = mid + 1; else hi = mid; }
        s_b = b;
        s_ord = i - lo;
    }
    __syncthreads();
    float v = (t < 128) ? g0[s_b * FD + t] : tab[s_ord * FD + (t - 128)];
    x1[(size_t)i * 256 + t] = (_Float16)fmaxf(v, 0.f);
}

// ---------------------------------------------------------------- merged weight transpose+convert (4 matrices, one launch)
__global__ void wconv_all_kernel(const float* __restrict__ W1, const float* __restrict__ W2,
                                 const float* __restrict__ W3, const float* __restrict__ Wg,
                                 _Float16* __restrict__ W1t, _Float16* __restrict__ W2t,
                                 _Float16* __restrict__ W3t, _Float16* __restrict__ Wgt) {
    __shared__ float tile[32][33];
    int b = blockIdx.x;
    const float* in; _Float16* out; int K, Nw, tid2;
    if (b < 128)      { in = W1; out = W1t; K = 256; Nw = 512; tid2 = b; }
    else if (b < 384) { in = W2; out = W2t; K = 512; Nw = 512; tid2 = b - 128; }
    else if (b < 640) { in = W3; out = W3t; K = 512; Nw = 512; tid2 = b - 384; }
    else              { in = Wg; out = Wgt; K = 512; Nw = 128; tid2 = b - 640; }
    int nxt = Nw / 32;
    int nb = (tid2 % nxt) * 32, kb = (tid2 / nxt) * 32;
    int tx = threadIdx.x & 31, ty = threadIdx.x >> 5;
    #pragma unroll
    for (int r = 0; r < 4; ++r)
        tile[ty + 8 * r][tx] = in[(size_t)(kb + ty + 8 * r) * Nw + nb + tx];
    __syncthreads();
    #pragma unroll
    for (int r = 0; r < 4; ++r)
        out[(size_t)(nb + ty + 8 * r) * K + kb + tx] = (_Float16)tile[tx][ty + 8 * r];
}

// ---------------------------------------------------------------- fp16 MFMA GEMM
// MODE 0: Y fp16 + fused s,d epilogue (nbx=4, col-block == head).
// MODE 1: fused out = (relu(acc+bg)) @ Wf + bf -> out[N][5]   (nbx=1, no Y write).
template <int MODE>
__global__ __launch_bounds__(256) void hgemm_kernel(
    const _Float16* __restrict__ X,   // [M][K] row-major
    const _Float16* __restrict__ Wt,  // [N][K] row-major
    const float* __restrict__ bias,   // MODE1: bg[128]
    const float* __restrict__ a_src,  // MODE0: [4][128]
    const float* __restrict__ a_dst,  // MODE0: [4][128]
    float* __restrict__ sbuf,         // MODE0: [NN][4]
    float* __restrict__ dbuf,         // MODE0
    const float* __restrict__ Wf,     // MODE1: [128][5]
    const float* __restrict__ bfv,    // MODE1: [5]
    void* __restrict__ Yv,
    int K, int ldy, int nbx) {
    __shared__ __align__(16) _Float16 As[2][128 * 32];
    __shared__ __align__(16) _Float16 Bs[2][128 * 32];
    __shared__ float red[5][128][2];
    const int lin = xcd_swz(blockIdx.x, gridDim.x);
    const int row0 = (lin / nbx) * 128;
    const int col0 = (lin % nbx) * 128;
    const int tid  = threadIdx.x;
    const int lane = tid & 63;
    const int wave = tid >> 6;
    const int wm = wave >> 1;
    const int wn = wave & 1;

    const int sr = tid >> 1;
    const int sq = (tid & 1) * 2;
    const size_t ga = (size_t)(row0 + sr) * K + sq * 8;
    const size_t gb = (size_t)(col0 + sr) * K + sq * 8;
    const int ss = (sr >> 1) & 3;
    const int w0 = sr * 32 + ((sq ^ ss) * 8);
    const int w1 = sr * 32 + (((sq + 1) ^ ss) * 8);

    const int kq  = lane >> 4;
    const int l15 = lane & 15;

    float4v acc[4][4];
    #pragma unroll
    for (int i = 0; i < 4; ++i)
        #pragma unroll
        for (int j = 0; j < 4; ++j)
            acc[i][j] = (float4v){0.f, 0.f, 0.f, 0.f};

    half8 ra0, ra1, rb0, rb1;
    ra0 = *(const half8*)&X[ga];      ra1 = *(const half8*)&X[ga + 8];
    rb0 = *(const half8*)&Wt[gb];     rb1 = *(const half8*)&Wt[gb + 8];
    *(half8*)&As[0][w0] = ra0;  *(half8*)&As[0][w1] = ra1;
    *(half8*)&Bs[0][w0] = rb0;  *(half8*)&Bs[0][w1] = rb1;

    const int nk = K >> 5;
    for (int ks = 0; ks < nk; ++ks) {
        __syncthreads();
        const int cur = ks & 1;
        if (ks + 1 < nk) {
            int kb = (ks + 1) << 5;
            ra0 = *(const half8*)&X[ga + kb];   ra1 = *(const half8*)&X[ga + kb + 8];
            rb0 = *(const half8*)&Wt[gb + kb];  rb1 = *(const half8*)&Wt[gb + kb + 8];
        }
        half8 af[4], bf[4];
        #pragma unroll
        for (int mi = 0; mi < 4; ++mi) {
            int r = wm * 64 + mi * 16 + l15;
            af[mi] = *(const half8*)&As[cur][r * 32 + ((kq ^ ((r >> 1) & 3)) * 8)];
        }
        #pragma unroll
        for (int ni = 0; ni < 4; ++ni) {
            int c = wn * 64 + ni * 16 + l15;
            bf[ni] = *(const half8*)&Bs[cur][c * 32 + ((kq ^ ((c >> 1) & 3)) * 8)];
        }
        #pragma unroll
        for (int mi = 0; mi < 4; ++mi)
            #pragma unroll
            for (int ni = 0; ni < 4; ++ni)
                acc[mi][ni] = __builtin_amdgcn_mfma_f32_16x16x32_f16(af[mi], bf[ni], acc[mi][ni], 0, 0, 0);
        if (ks + 1 < nk) {
            const int nxt2 = cur ^ 1;
            *(half8*)&As[nxt2][w0] = ra0;  *(half8*)&As[nxt2][w1] = ra1;
            *(half8*)&Bs[nxt2][w0] = rb0;  *(half8*)&Bs[nxt2][w1] = rb1;
        }
    }

    // C/D layout: col = l15, row = (lane>>4)*4 + j  (within each 16x16 tile)
    if (MODE == 0) {
        const int h = col0 >> 7;   // head index
        float asv[4], adv[4];
        #pragma unroll
        for (int ni = 0; ni < 4; ++ni) {
            int ch = wn * 64 + ni * 16 + l15;
            asv[ni] = a_src[h * FD + ch];
            adv[ni] = a_dst[h * FD + ch];
        }
        #pragma unroll
        for (int mi = 0; mi < 4; ++mi) {
            int rb = row0 + wm * 64 + mi * 16 + ((lane >> 4) << 2);
            #pragma unroll
            for (int j = 0; j < 4; ++j) {
                float ps = 0.f, pd = 0.f;
                #pragma unroll
                for (int ni = 0; ni < 4; ++ni) {
                    float v = acc[mi][ni][j];
                    int c = col0 + wn * 64 + ni * 16 + l15;
                    ((_Float16*)Yv)[(size_t)(rb + j) * ldy + c] = (_Float16)v;
                    ps += v * asv[ni];
                    pd += v * adv[ni];
                }
                #pragma unroll
                for (int m = 8; m >= 1; m >>= 1) {
                    ps += __shfl_xor(ps, m);
                    pd += __shfl_xor(pd, m);
                }
                if (l15 == 0) {
                    int rloc = wm * 64 + mi * 16 + ((lane >> 4) << 2) + j;
                    red[0][rloc][wn] = ps;
                    red[1][rloc][wn] = pd;
                }
            }
        }
        __syncthreads();
        if (tid < 128) {
            sbuf[(size_t)(row0 + tid) * 4 + h] = red[0][tid][0] + red[0][tid][1];
            dbuf[(size_t)(row0 + tid) * 4 + h] = red[1][tid][0] + red[1][tid][1];
        }
    } else {
        float bgv[4], wf[4][5];
        #pragma unroll
        for (int ni = 0; ni < 4; ++ni) {
            int c = wn * 64 + ni * 16 + l15;
            bgv[ni] = bias[c];
            #pragma unroll
            for (int q = 0; q < 5; ++q) wf[ni][q] = Wf[c * 5 + q];
        }
        #pragma unroll
        for (int mi = 0; mi < 4; ++mi) {
            #pragma unroll
            for (int j = 0; j < 4; ++j) {
                float vr[4];
                #pragma unroll
                for (int ni = 0; ni < 4; ++ni)
                    vr[ni] = fmaxf(acc[mi][ni][j] + bgv[ni], 0.f);
                #pragma unroll
                for (int q = 0; q < 5; ++q) {
                    float p = vr[0] * wf[0][q] + vr[1] * wf[1][q] + vr[2] * wf[2][q] + vr[3] * wf[3][q];
                    #pragma unroll
                    for (int m = 8; m >= 1; m >>= 1) p += __shfl_xor(p, m);
                    if (l15 == 0) {
                        int rloc = wm * 64 + mi * 16 + ((lane >> 4) << 2) + j;
                        red[q][rloc][wn] = p;
                    }
                }
            }
        }
        __syncthreads();
        if (tid < 128) {
            float* o = (float*)Yv;
            #pragma unroll
            for (int q = 0; q < 5; ++q)
                o[(size_t)(row0 + tid) * 5 + q] = red[q][tid][0] + red[q][tid][1] + bfv[q];
        }
    }
}

// ---------------------------------------------------------------- attention + aggregation (wave-per-node, fp16)
__global__ void agg_kernel(const _Float16* __restrict__ xl,
                           const float* __restrict__ s, const float* __restrict__ d,
                           const int* __restrict__ esrc,
                           const float* __restrict__ bias,
                           _Float16* __restrict__ xout) {
    int wave = threadIdx.x >> 6;
    int lane = threadIdx.x & 63;
    int blk = xcd_swz(blockIdx.x, gridDim.x);
    int i = blk * 4 + wave;
    int h = lane >> 4;

    int sk = (lane < 8) ? esrc[i * DEG + lane] : i;
    int srcs[9];
    #pragma unroll
    for (int k = 0; k < 9; ++k) srcs[k] = __shfl(sk, k);

    float dh = d[i * 4 + h];
    float e[9];
    float m = -1e30f;
    #pragma unroll
    for (int k = 0; k < 9; ++k) {
        float v = s[srcs[k] * 4 + h] + dh;
        v = (v >= 0.f) ? v : NEG_SLOPE * v;
        e[k] = v;
        m = fmaxf(m, v);
    }
    float den = 0.f;
    #pragma unroll
    for (int k = 0; k < 9; ++k) { e[k] = __expf(e[k] - m); den += e[k]; }
    float inv = 1.f / (den + 1e-16f);

    int c0 = lane * 8;
    float acc[8] = {};
    #pragma unroll
    for (int k = 0; k < 9; ++k) {
        half8 x = *(const half8*)&xl[(size_t)srcs[k] * HFD + c0];
        float a = e[k] * inv;
        #pragma unroll
        for (int j = 0; j < 8; ++j) acc[j] += a * (float)x[j];
    }
    float4v b0 = *(const float4v*)&bias[c0];
    float4v b1 = *(const float4v*)&bias[c0 + 4];
    half8 o;
    #pragma unroll
    for (int j = 0; j < 4; ++j) {
        o[j]     = (_Float16)fmaxf(acc[j] + b0[j], 0.f);
        o[j + 4] = (_Float16)fmaxf(acc[j + 4] + b1[j], 0.f);
    }
    *(half8*)&xout[(size_t)i * HFD + c0] = o;
}

// ----------------------------------------------------------------
extern "C" void kernel_launch(void* const* d_in, const int* in_sizes, int n_in,
                              void* d_out, int out_size, void* d_ws, size_t ws_size,
                              hipStream_t stream) {
    const float* z    = (const float*)d_in[0];
    const int*  eidx  = (const int*)d_in[1];
    const int*  batch = (const int*)d_in[2];
    const float* W0  = (const float*)d_in[3];
    const float* b0  = (const float*)d_in[4];
    const float* W1  = (const float*)d_in[5];
    const float* as1 = (const float*)d_in[6];
    const float* ad1 = (const float*)d_in[7];
    const float* b1  = (const float*)d_in[8];
    const float* W2  = (const float*)d_in[9];
    const float* as2 = (const float*)d_in[10];
    const float* ad2 = (const float*)d_in[11];
    const float* b2  = (const float*)d_in[12];
    const float* W3  = (const float*)d_in[13];
    const float* as3 = (const float*)d_in[14];
    const float* ad3 = (const float*)d_in[15];
    const float* b3  = (const float*)d_in[16];
    const float* Wg  = (const float*)d_in[17];
    const float* bg  = (const float*)d_in[18];
    const float* Wf  = (const float*)d_in[19];
    const float* bfv = (const float*)d_in[20];
    float* out = (float*)d_out;

    float* ws   = (float*)d_ws;
    float* tab  = ws;                          // 23040
    float* g0   = tab + 23040;                 // 32768
    float* sbuf = g0 + 32768;                  // NN*4
    float* dbuf = sbuf + (size_t)NN * 4;       // NN*4
    _Float16* Yh  = (_Float16*)(dbuf + (size_t)NN * 4);    // NN*512 fp16
    _Float16* Xh  = Yh + (size_t)NN * 512;     // NN*512 fp16
    _Float16* W1t = Xh + (size_t)NN * 512;     // 512*256
    _Float16* W2t = W1t + 512 * 256;           // 512*512
    _Float16* W3t = W2t + 512 * 512;           // 512*512
    _Float16* Wgt = W3t + 512 * 512;           // 128*512

    sintab_kernel<<<MAXPOS, FD, 0, stream>>>(tab);
    g0_kernel<<<N_GRAPHS, FD, 0, stream>>>(z, W0, b0, g0);
    build_x1_kernel<<<NN, 256, 0, stream>>>(g0, tab, batch, Xh);
    wconv_all_kernel<<<704, 256, 0, stream>>>(W1, W2, W3, Wg, W1t, W2t, W3t, Wgt);

    const int nbL = (NN / 128) * (HFD / 128);  // 800 blocks
    const int nbH = (NN / 128) * (FD / 128);   // 200 blocks

    // ---- layer 1 (K=256): GEMM + fused s,d
    hgemm_kernel<0><<<nbL, 256, 0, stream>>>(Xh, W1t, nullptr, as1, ad1, sbuf, dbuf, nullptr, nullptr, Yh, 256, HFD, HFD / 128);
    agg_kernel<<<NN / 4, 256, 0, stream>>>(Yh, sbuf, dbuf, eidx, b1, Xh);

    // ---- layer 2 (K=512)
    hgemm_kernel<0><<<nbL, 256, 0, stream>>>(Xh, W2t, nullptr, as2, ad2, sbuf, dbuf, nullptr, nullptr, Yh, 512, HFD, HFD / 128);
    agg_kernel<<<NN / 4, 256, 0, stream>>>(Yh, sbuf, dbuf, eidx, b2, Xh);

    // ---- layer 3 (K=512)
    hgemm_kernel<0><<<nbL, 256, 0, stream>>>(Xh, W3t, nullptr, as3, ad3, sbuf, dbuf, nullptr, nullptr, Yh, 512, HFD, HFD / 128);
    agg_kernel<<<NN / 4, 256, 0, stream>>>(Yh, sbuf, dbuf, eidx, b3, Xh);

    // ---- gather head + final projection fused: out = relu(x@Wg+bg) @ Wf + bf
    hgemm_kernel<1><<<nbH, 256, 0, stream>>>(Xh, Wgt, bg, nullptr, nullptr, nullptr, nullptr, Wf, bfv, out, 512, 5, FD / 128);
}